// Round 5
// baseline (50.867 us; speedup 1.0000x reference)
//
#include <hip/hip_runtime.h>
#include <stdint.h>

// MetricLoss: B=1024, M=32, F=256, K_GRP=4
// out[0] = (1/1536) * sum_{same-group pairs i<j, m} ||x_i,m - x_j,m||^2
// out[1] = (1/522240) * sum_{g_i<g_j, m} relu(1 - ||x_i,m - x_j,m||^2)
//
// ws layout:
//   [0,        16 MiB)   : xb  bf16 [32][1024][256]  (per-m contiguous matrices)
//   [16 MiB,  +128 KiB)  : sq  f32  [32][1024]
//   [+32 KiB]            : homo_part  f32 [8192]
//   [+1 KiB]             : heter_part f32 [256]

typedef __attribute__((ext_vector_type(4))) float f32x4;
typedef __attribute__((ext_vector_type(8))) short bf16x8;

#define XB_OFF    0u
#define SQ_OFF    16777216u
#define HOMO_OFF  16908288u   // 8192 floats
#define HETER_OFF 16941056u   // 256 floats

#define AS1 __attribute__((address_space(1)))
#define AS3 __attribute__((address_space(3)))

__device__ __forceinline__ void async16(const void* g, void* l) {
  __builtin_amdgcn_global_load_lds((const AS1 unsigned int*)(uintptr_t)g,
                                   (AS3 unsigned int*)(uintptr_t)l, 16, 0, 0);
}

__device__ __forceinline__ unsigned short f2bf(float f) {
  union { float f; unsigned u; } v; v.f = f;
  return (unsigned short)((v.u + 0x7fffu + ((v.u >> 16) & 1u)) >> 16);
}

// ---- Kernel 1 (fused convert + homo) — unchanged (HBM-BW-bound, ~8 us)
__global__ __launch_bounds__(256) void k_fused(const float* __restrict__ x,
                                               unsigned short* __restrict__ xb,
                                               float* __restrict__ sq,
                                               float* __restrict__ homo_part) {
  const int task = blockIdx.x * 4 + (threadIdx.x >> 6);  // task = g*32 + m
  const int lane = threadIdx.x & 63;
  const int g = task >> 5;
  const int m = task & 31;

  const float* base = x + ((size_t)(g * 4) * 32 + m) * 256 + lane * 4;
  float4 v[4];
  float sqv[4];
  #pragma unroll
  for (int a = 0; a < 4; ++a) {
    v[a] = *(const float4*)(base + a * 8192);
    float s = v[a].x * v[a].x + v[a].y * v[a].y + v[a].z * v[a].z + v[a].w * v[a].w;
    #pragma unroll
    for (int off = 32; off; off >>= 1) s += __shfl_xor(s, off, 64);
    sqv[a] = s;
    const int i = g * 4 + a;
    if (lane == 0) sq[m * 1024 + i] = s;
    ushort4 o;
    o.x = f2bf(v[a].x); o.y = f2bf(v[a].y); o.z = f2bf(v[a].z); o.w = f2bf(v[a].w);
    *(ushort4*)(xb + ((size_t)(m * 1024 + i)) * 256 + lane * 4) = o;
  }
  const float sx = v[0].x + v[1].x + v[2].x + v[3].x;
  const float sy = v[0].y + v[1].y + v[2].y + v[3].y;
  const float sz = v[0].z + v[1].z + v[2].z + v[3].z;
  const float sw = v[0].w + v[1].w + v[2].w + v[3].w;
  float s = sx * sx + sy * sy + sz * sz + sw * sw;
  #pragma unroll
  for (int off = 32; off; off >>= 1) s += __shfl_xor(s, off, 64);
  if (lane == 0)
    homo_part[task] = 4.f * (sqv[0] + sqv[1] + sqv[2] + sqv[3]) - s;
}

// Stage one K-half (128 rows x 128 k, 32 KB) of a B panel into an LDS buffer.
// Row-XOR chunk swizzle (16B chunks): LDS chunk (r,c) holds global chunk c^(r&7).
__device__ __forceinline__ void stage_bhalf(const unsigned short* __restrict__ Xp,
                                            int kh, unsigned short* buf, int tid) {
  #pragma unroll
  for (int i = 0; i < 8; ++i) {
    const int ch = i * 256 + tid;          // 2048 chunks of 16B
    const int rr = ch >> 4;
    const int c  = ch & 15;
    const int gc = c ^ (rr & 7);
    async16(Xp + (size_t)rr * 256 + kh * 128 + gc * 8, (char*)buf + ch * 16);
  }
}

// ---- Kernel 2: heter loss, row-band resident.
// Block (m, rb): A panel (128 x 256, 64 KB) LDS-resident + sq row (4 KB) staged
// once; B panels cb=rb..7 streamed as 32 KB K-halves through a 2x32 KB double
// buffer with counted vmcnt(8) waits. Grid = 256 = 1 block/CU, single round;
// all 8 rb-blocks of one m share an XCD (d&7 affine) for L2 panel sharing.
__global__ __launch_bounds__(256) void k_heter(const unsigned short* __restrict__ xb,
                                               const float* __restrict__ sq,
                                               float* __restrict__ heter_part) {
  const int d  = blockIdx.x;                 // 256 blocks
  const int m  = (d & 7) * 4 + ((d >> 3) & 3);
  const int rb = d >> 5;
  const int S  = 2 * (7 - rb);               // streamed B halves

  __shared__ __align__(16) unsigned short ldsA[32768];    // 64 KB: A, full K
  __shared__ __align__(16) unsigned short ldsB0[16384];   // 32 KB half buffers
  __shared__ __align__(16) unsigned short ldsB1[16384];
  __shared__ __align__(16) float sql[1024];               // 4 KB: sq row of m
  __shared__ float part[4];

  const int tid  = threadIdx.x;
  const int lane = tid & 63;
  const int wid  = tid >> 6;
  const int wr = wid >> 1, wc = wid & 1;     // 2x2 waves, each 64x64 output
  const int fr = lane & 15;                  // fragment row/col within 16
  const int kg = lane >> 4;                  // k-group

  const unsigned short* Xm = xb + (size_t)m * 1024 * 256;
  const unsigned short* Xa = Xm + (size_t)rb * 128 * 256;

  // stage A (full K, row-XOR swizzled: 32 chunks/row) + sq row
  #pragma unroll
  for (int i = 0; i < 16; ++i) {
    const int ch = i * 256 + tid;            // 4096 chunks
    const int rr = ch >> 5;
    const int c  = ch & 31;
    const int gc = (c & 7) ^ (rr & 7) | (c & 24);  // XOR low 3 bits only
    async16(Xa + (size_t)rr * 256 + gc * 8, (char*)ldsA + ch * 16);
  }
  async16(sq + m * 1024 + tid * 4, (char*)sql + tid * 16);

  if (S > 0) {
    const unsigned short* Xb0 = Xm + (size_t)(rb + 1) * 128 * 256;
    stage_bhalf(Xb0, 0, ldsB0, tid);
    stage_bhalf(Xb0, 1, ldsB1, tid);
    asm volatile("s_waitcnt vmcnt(16)" ::: "memory");  // A + sq landed
  } else {
    asm volatile("s_waitcnt vmcnt(0)" ::: "memory");
  }
  __builtin_amdgcn_s_barrier();

  const int ibase = rb * 128 + wr * 64;
  float sqi[4][4];
  #pragma unroll
  for (int ai = 0; ai < 4; ++ai)
    #pragma unroll
    for (int rg = 0; rg < 4; ++rg)
      sqi[ai][rg] = sql[ibase + ai * 16 + kg * 4 + rg];

  float local = 0.f;

  // ---- diag tile (B == A, both operands from ldsA)
  {
    f32x4 acc[4][4] = {};
    #pragma unroll
    for (int kkg = 0; kkg < 8; ++kkg) {
      bf16x8 af[4], bv[4];
      #pragma unroll
      for (int q = 0; q < 4; ++q) {
        const int ra = wr * 64 + q * 16 + fr;
        af[q] = *(const bf16x8*)(ldsA + ra * 256 + ((((kkg << 2) + kg) ^ (ra & 7))) * 8);
        const int rbw = wc * 64 + q * 16 + fr;
        bv[q] = *(const bf16x8*)(ldsA + rbw * 256 + ((((kkg << 2) + kg) ^ (rbw & 7))) * 8);
      }
      #pragma unroll
      for (int ai = 0; ai < 4; ++ai)
        #pragma unroll
        for (int bj = 0; bj < 4; ++bj)
          acc[ai][bj] = __builtin_amdgcn_mfma_f32_16x16x32_bf16(af[ai], bv[bj],
                                                                acc[ai][bj], 0, 0, 0);
    }
    const int jbase = rb * 128 + wc * 64;
    #pragma unroll
    for (int bj = 0; bj < 4; ++bj) {
      const int j = jbase + bj * 16 + fr;
      const float sqj = sql[j];
      const int gj = j >> 2;
      #pragma unroll
      for (int ai = 0; ai < 4; ++ai)
        #pragma unroll
        for (int rg = 0; rg < 4; ++rg) {
          const int i = ibase + ai * 16 + kg * 4 + rg;
          const float dd = sqi[ai][rg] + sqj - 2.f * acc[ai][bj][rg];
          const float v = 1.f - dd;
          if (v > 0.f && gj > (i >> 2)) local += v;
        }
    }
  }

  // ---- streamed tiles cb = rb+1 .. 7
  int s = 0;
  for (int cb = rb + 1; cb <= 7; ++cb) {
    f32x4 acc[4][4] = {};
    #pragma unroll
    for (int h = 0; h < 2; ++h, ++s) {
      if (s + 1 < S) { asm volatile("s_waitcnt vmcnt(8)" ::: "memory"); }
      else           { asm volatile("s_waitcnt vmcnt(0)" ::: "memory"); }
      __builtin_amdgcn_s_barrier();          // H_s visible to all waves
      const unsigned short* lB = h ? ldsB1 : ldsB0;
      #pragma unroll
      for (int kk = 0; kk < 4; ++kk) {
        bf16x8 af[4], bv[4];
        #pragma unroll
        for (int q = 0; q < 4; ++q) {
          const int ra = wr * 64 + q * 16 + fr;
          const int ccA = (h * 4 + kk) * 4 + kg;
          af[q] = *(const bf16x8*)(ldsA + ra * 256 + ((ccA ^ (ra & 7))) * 8);
          const int rbw = wc * 64 + q * 16 + fr;
          const int ccB = kk * 4 + kg;
          bv[q] = *(const bf16x8*)(lB + rbw * 128 + ((ccB ^ (rbw & 7))) * 8);
        }
        #pragma unroll
        for (int ai = 0; ai < 4; ++ai)
          #pragma unroll
          for (int bj = 0; bj < 4; ++bj)
            acc[ai][bj] = __builtin_amdgcn_mfma_f32_16x16x32_bf16(af[ai], bv[bj],
                                                                  acc[ai][bj], 0, 0, 0);
      }
      __builtin_amdgcn_s_barrier();          // all waves done reading this buffer
      if (s + 2 < S)                         // prefetch H_{s+2} into the freed buffer
        stage_bhalf(Xm + (size_t)(cb + 1) * 128 * 256, h, h ? ldsB1 : ldsB0, tid);
    }
    const int jbase = cb * 128 + wc * 64;
    #pragma unroll
    for (int bj = 0; bj < 4; ++bj) {
      const int j = jbase + bj * 16 + fr;
      const float sqj = sql[j];
      const int gj = j >> 2;
      #pragma unroll
      for (int ai = 0; ai < 4; ++ai)
        #pragma unroll
        for (int rg = 0; rg < 4; ++rg) {
          const int i = ibase + ai * 16 + kg * 4 + rg;
          const float dd = sqi[ai][rg] + sqj - 2.f * acc[ai][bj][rg];
          const float v = 1.f - dd;
          if (v > 0.f && gj > (i >> 2)) local += v;
        }
    }
  }

  #pragma unroll
  for (int off = 32; off; off >>= 1) local += __shfl_xor(local, off, 64);
  if (lane == 0) part[wid] = local;
  __syncthreads();
  if (tid == 0)
    heter_part[d] = part[0] + part[1] + part[2] + part[3];
}

// ---- Kernel 3: final reduction of partials + scaling (single block)
__global__ __launch_bounds__(256) void k_final(const float* __restrict__ homo_part,
                                               const float* __restrict__ heter_part,
                                               float* __restrict__ out) {
  __shared__ float red[8];
  const int tid = threadIdx.x;
  const int lane = tid & 63;
  const int wid = tid >> 6;

  float h = 0.f;
  for (int i = tid; i < 8192; i += 256) h += homo_part[i];
  #pragma unroll
  for (int off = 32; off; off >>= 1) h += __shfl_xor(h, off, 64);
  if (lane == 0) red[wid] = h;

  float e = heter_part[tid];
  #pragma unroll
  for (int off = 32; off; off >>= 1) e += __shfl_xor(e, off, 64);
  if (lane == 0) red[4 + wid] = e;

  __syncthreads();
  if (tid == 0) out[0] = (red[0] + red[1] + red[2] + red[3]) * (1.0f / 1536.0f);
  if (tid == 1) out[1] = (red[4] + red[5] + red[6] + red[7]) * (1.0f / 522240.0f);
}

extern "C" void kernel_launch(void* const* d_in, const int* in_sizes, int n_in,
                              void* d_out, int out_size, void* d_ws, size_t ws_size,
                              hipStream_t stream) {
  const float* x = (const float*)d_in[0];
  float* out = (float*)d_out;
  char* ws = (char*)d_ws;
  unsigned short* xb = (unsigned short*)(ws + XB_OFF);
  float* sq         = (float*)(ws + SQ_OFF);
  float* homo_part  = (float*)(ws + HOMO_OFF);
  float* heter_part = (float*)(ws + HETER_OFF);

  k_fused<<<2048, 256, 0, stream>>>(x, xb, sq, homo_part);
  k_heter<<<256, 256, 0, stream>>>(xb, sq, heter_part);
  k_final<<<1, 256, 0, stream>>>(homo_part, heter_part, out);
}

// Round 6
// 49.864 us; speedup vs baseline: 1.0201x; 1.0201x over previous
//
#include <hip/hip_runtime.h>
#include <stdint.h>

// MetricLoss: B=1024, M=32, F=256, K_GRP=4
// out[0] = (1/1536) * sum_{same-group pairs i<j, m} ||x_i,m - x_j,m||^2
// out[1] = (1/522240) * sum_{g_i<g_j, m} relu(1 - ||x_i,m - x_j,m||^2)
//
// ws layout:
//   [0,        16 MiB)   : xb  bf16 [32][1024][256]  (per-m contiguous matrices)
//   [16 MiB,  +128 KiB)  : sq  f32  [32][1024]
//   [+32 KiB]            : homo_part  f32 [8192]
//   [+1.5 KiB]           : heter_part f32 [384]

typedef __attribute__((ext_vector_type(4))) float f32x4;
typedef __attribute__((ext_vector_type(8))) short bf16x8;

#define XB_OFF    0u
#define SQ_OFF    16777216u
#define HOMO_OFF  16908288u   // 8192 floats
#define HETER_OFF 16941056u   // 384 floats

#define AS1 __attribute__((address_space(1)))
#define AS3 __attribute__((address_space(3)))

__device__ __forceinline__ void async16(const void* g, void* l) {
  __builtin_amdgcn_global_load_lds((const AS1 unsigned int*)(uintptr_t)g,
                                   (AS3 unsigned int*)(uintptr_t)l, 16, 0, 0);
}

__device__ __forceinline__ unsigned short f2bf(float f) {
  union { float f; unsigned u; } v; v.f = f;
  return (unsigned short)((v.u + 0x7fffu + ((v.u >> 16) & 1u)) >> 16);
}

// ---- Kernel 1 (fused convert + homo) — unchanged (HBM-BW-bound, ~8-10 us)
__global__ __launch_bounds__(256) void k_fused(const float* __restrict__ x,
                                               unsigned short* __restrict__ xb,
                                               float* __restrict__ sq,
                                               float* __restrict__ homo_part) {
  const int task = blockIdx.x * 4 + (threadIdx.x >> 6);  // task = g*32 + m
  const int lane = threadIdx.x & 63;
  const int g = task >> 5;
  const int m = task & 31;

  const float* base = x + ((size_t)(g * 4) * 32 + m) * 256 + lane * 4;
  float4 v[4];
  float sqv[4];
  #pragma unroll
  for (int a = 0; a < 4; ++a) {
    v[a] = *(const float4*)(base + a * 8192);
    float s = v[a].x * v[a].x + v[a].y * v[a].y + v[a].z * v[a].z + v[a].w * v[a].w;
    #pragma unroll
    for (int off = 32; off; off >>= 1) s += __shfl_xor(s, off, 64);
    sqv[a] = s;
    const int i = g * 4 + a;
    if (lane == 0) sq[m * 1024 + i] = s;
    ushort4 o;
    o.x = f2bf(v[a].x); o.y = f2bf(v[a].y); o.z = f2bf(v[a].z); o.w = f2bf(v[a].w);
    *(ushort4*)(xb + ((size_t)(m * 1024 + i)) * 256 + lane * 4) = o;
  }
  const float sx = v[0].x + v[1].x + v[2].x + v[3].x;
  const float sy = v[0].y + v[1].y + v[2].y + v[3].y;
  const float sz = v[0].z + v[1].z + v[2].z + v[3].z;
  const float sw = v[0].w + v[1].w + v[2].w + v[3].w;
  float s = sx * sx + sy * sy + sz * sz + sw * sw;
  #pragma unroll
  for (int off = 32; off; off >>= 1) s += __shfl_xor(s, off, 64);
  if (lane == 0)
    homo_part[task] = 4.f * (sqv[0] + sqv[1] + sqv[2] + sqv[3]) - s;
}

// ---- Kernel 2: heter loss. A row-band panel in LDS (row-XOR swizzled, the
// R5-verified layout); B fragments read DIRECTLY from global (L2-resident:
// all 12 blocks of an m share one XCD via grid linearization m + 32*chunk).
// No barriers / no vmcnt asm in the K-loop; 1-deep register prefetch for B.
__global__ __launch_bounds__(256, 2) void k_heter(const unsigned short* __restrict__ xb,
                                                  const float* __restrict__ sq,
                                                  float* __restrict__ heter_part) {
  const int m     = blockIdx.x;   // 32
  const int chunk = blockIdx.y;   // 12 chunks of 3 triangle tiles

  __shared__ __align__(16) unsigned short ldsA[32768];  // 64 KB: A band, full K
  __shared__ __align__(16) float sql[1024];             // 4 KB: sq row of m
  __shared__ float part[4];

  const int tid  = threadIdx.x;
  const int lane = tid & 63;
  const int wid  = tid >> 6;
  const int wr = wid >> 1, wc = wid & 1;   // 2x2 waves, each 64x64 output
  const int fr = lane & 15;                // fragment row/col within 16
  const int kg = lane >> 4;                // k-group (8 contiguous k per lane)

  const unsigned short* Xm = xb + (size_t)m * 1024 * 256;

  float local = 0.f;
  int curA = -1;

  for (int u = 0; u < 3; ++u) {
    int t = chunk * 3 + u, r = 0;          // decode triangle tile (r,c), c>=r
    while (t >= 8 - r) { t -= 8 - r; ++r; }
    const int c = r + t;

    if (r != curA) {                       // (re)stage A band r: <=2 per block
      __syncthreads();                     // all waves done reading old A
      const unsigned short* Xa = Xm + (size_t)r * 128 * 256;
      #pragma unroll
      for (int i = 0; i < 16; ++i) {
        const int ch = i * 256 + tid;      // 4096 chunks of 16B
        const int rr = ch >> 5, cc = ch & 31;
        const int gc = ((cc & 7) ^ (rr & 7)) | (cc & 24);
        async16(Xa + (size_t)rr * 256 + gc * 8, (char*)ldsA + ch * 16);
      }
      if (curA < 0) async16(sq + m * 1024 + tid * 4, (char*)sql + tid * 16);
      asm volatile("s_waitcnt vmcnt(0)" ::: "memory");
      __syncthreads();
      curA = r;
    }

    const bool diag = (c == r);
    if (diag && wr == 1 && wc == 0) continue;  // j<64<=i -> gj>gi never: zero

    f32x4 acc[4][4] = {};

    if (diag) {
      // both operands from ldsA (swizzled reads, verified in R5)
      #pragma unroll
      for (int kk = 0; kk < 8; ++kk) {
        bf16x8 af[4], bv[4];
        #pragma unroll
        for (int q = 0; q < 4; ++q) {
          const int ra = wr * 64 + q * 16 + fr;
          af[q] = *(const bf16x8*)(ldsA + ra * 256 + ((((kk << 2) + kg) ^ (ra & 7))) * 8);
          const int rb = wc * 64 + q * 16 + fr;
          bv[q] = *(const bf16x8*)(ldsA + rb * 256 + ((((kk << 2) + kg) ^ (rb & 7))) * 8);
        }
        #pragma unroll
        for (int ai = 0; ai < 4; ++ai)
          #pragma unroll
          for (int bj = 0; bj < 4; ++bj)
            acc[ai][bj] = __builtin_amdgcn_mfma_f32_16x16x32_bf16(af[ai], bv[bj],
                                                                  acc[ai][bj], 0, 0, 0);
      }
    } else {
      // B fragments straight from global (L2-hit), 1-deep register prefetch
      const unsigned short* Bp = Xm + (size_t)c * 128 * 256
                                    + (size_t)(wc * 64 + fr) * 256 + kg * 8;
      bf16x8 bb[2][4];
      #pragma unroll
      for (int q = 0; q < 4; ++q)
        bb[0][q] = *(const bf16x8*)(Bp + q * 4096);
      #pragma unroll
      for (int kk = 0; kk < 8; ++kk) {
        if (kk < 7) {
          #pragma unroll
          for (int q = 0; q < 4; ++q)
            bb[(kk + 1) & 1][q] = *(const bf16x8*)(Bp + q * 4096 + (kk + 1) * 32);
        }
        bf16x8 af[4];
        #pragma unroll
        for (int q = 0; q < 4; ++q) {
          const int ra = wr * 64 + q * 16 + fr;
          af[q] = *(const bf16x8*)(ldsA + ra * 256 + ((((kk << 2) + kg) ^ (ra & 7))) * 8);
        }
        #pragma unroll
        for (int ai = 0; ai < 4; ++ai)
          #pragma unroll
          for (int bj = 0; bj < 4; ++bj)
            acc[ai][bj] = __builtin_amdgcn_mfma_f32_16x16x32_bf16(af[ai], bb[kk & 1][bj],
                                                                  acc[ai][bj], 0, 0, 0);
      }
    }

    // epilogue: relu(1 - (sq_i + sq_j - 2*dot)), strict group mask
    const int ibase = r * 128 + wr * 64;
    const int jbase = c * 128 + wc * 64;
    float sqi[4][4];
    #pragma unroll
    for (int ai = 0; ai < 4; ++ai)
      #pragma unroll
      for (int rg = 0; rg < 4; ++rg)
        sqi[ai][rg] = sql[ibase + ai * 16 + kg * 4 + rg];
    #pragma unroll
    for (int bj = 0; bj < 4; ++bj) {
      const int j = jbase + bj * 16 + fr;       // C/D: col = lane&15
      const float sqj = sql[j];
      const int gj = j >> 2;
      #pragma unroll
      for (int ai = 0; ai < 4; ++ai)
        #pragma unroll
        for (int rg = 0; rg < 4; ++rg) {
          const int i = ibase + ai * 16 + kg * 4 + rg;  // row = (lane>>4)*4 + reg
          const float dd = sqi[ai][rg] + sqj - 2.f * acc[ai][bj][rg];
          const float v = 1.f - dd;
          if (v > 0.f && gj > (i >> 2)) local += v;
        }
    }
  }

  #pragma unroll
  for (int off = 32; off; off >>= 1) local += __shfl_xor(local, off, 64);
  if (lane == 0) part[wid] = local;
  __syncthreads();
  if (tid == 0)
    heter_part[blockIdx.y * 32 + blockIdx.x] = part[0] + part[1] + part[2] + part[3];
}

// ---- Kernel 3: final reduction of partials + scaling (single block)
__global__ __launch_bounds__(256) void k_final(const float* __restrict__ homo_part,
                                               const float* __restrict__ heter_part,
                                               float* __restrict__ out) {
  __shared__ float red[8];
  const int tid = threadIdx.x;
  const int lane = tid & 63;
  const int wid = tid >> 6;

  float h = 0.f;
  for (int i = tid; i < 8192; i += 256) h += homo_part[i];
  #pragma unroll
  for (int off = 32; off; off >>= 1) h += __shfl_xor(h, off, 64);
  if (lane == 0) red[wid] = h;

  float e = heter_part[tid] + ((tid < 128) ? heter_part[256 + tid] : 0.f);
  #pragma unroll
  for (int off = 32; off; off >>= 1) e += __shfl_xor(e, off, 64);
  if (lane == 0) red[4 + wid] = e;

  __syncthreads();
  if (tid == 0) out[0] = (red[0] + red[1] + red[2] + red[3]) * (1.0f / 1536.0f);
  if (tid == 1) out[1] = (red[4] + red[5] + red[6] + red[7]) * (1.0f / 522240.0f);
}

extern "C" void kernel_launch(void* const* d_in, const int* in_sizes, int n_in,
                              void* d_out, int out_size, void* d_ws, size_t ws_size,
                              hipStream_t stream) {
  const float* x = (const float*)d_in[0];
  float* out = (float*)d_out;
  char* ws = (char*)d_ws;
  unsigned short* xb = (unsigned short*)(ws + XB_OFF);
  float* sq         = (float*)(ws + SQ_OFF);
  float* homo_part  = (float*)(ws + HOMO_OFF);
  float* heter_part = (float*)(ws + HETER_OFF);

  k_fused<<<2048, 256, 0, stream>>>(x, xb, sq, homo_part);
  k_heter<<<dim3(32, 12), 256, 0, stream>>>(xb, sq, heter_part);
  k_final<<<1, 256, 0, stream>>>(homo_part, heter_part, out);
}